// Round 5
// baseline (12973.474 us; speedup 1.0000x reference)
//
#include <hip/hip_runtime.h>
#include <math.h>

// ReservoirLayer: B=8, T=4096, R=1024, F=64, I=32
#define TT 4096
#define RR 1024
#define FF 64
#define II 32
#define GROUPS 8                 // one group per batch element
#define BPG 32                   // blocks per group
#define THREADS 256
#define KV4 32                   // float4 of W_hh per thread
#define ALPHA 0.9f

typedef unsigned long long u64;
typedef unsigned int u32;

#define SLOT_U32 (GROUPS * RR)           // 8192 u32 per parity slot (32 KB)
#define PAD(i) ((i) + (((i) >> 7) << 2)) // +4 floats per 128-float chunk
#define TAGMASK 0x0000000100000001ull

__device__ __forceinline__ u64 ld_rlx64(const u64* p) {
    return __hip_atomic_load(p, __ATOMIC_RELAXED, __HIP_MEMORY_SCOPE_AGENT);
}
__device__ __forceinline__ void st_rlx32(u32* p, u32 v) {
    __hip_atomic_store(p, v, __ATOMIC_RELAXED, __HIP_MEMORY_SCOPE_AGENT);
}

// tanh(x) = 1 - 2/(e^{2x}+1); v_exp_f32 computes 2^x so scale by 2*log2(e).
// Exact at +/-inf (inf -> 1, 0 -> -1), ~1e-6 abs error, ~5 VALU vs tanhf's
// branchy libcall — this sits on the serial recurrence path.
__device__ __forceinline__ float fast_tanh(float x) {
    float e, r;
    asm("v_exp_f32 %0, %1" : "=v"(e) : "v"(x * 2.8853900817779268f));
    asm("v_rcp_f32 %0, %1" : "=v"(r) : "v"(e + 1.0f));
    return fmaf(-2.0f, r, 1.0f);
}

__global__ __launch_bounds__(THREADS, 1)
void reservoir_df(const float* __restrict__ feedback,
                  const float* __restrict__ driving,
                  const float* __restrict__ W_fb,
                  const float* __restrict__ W_in,
                  const float* __restrict__ W_hh,
                  const float* __restrict__ bias,
                  float* __restrict__ out,
                  u32* __restrict__ hbuf)
{
    const int tid  = threadIdx.x;
    const int bid  = blockIdx.x;
    const int g    = bid & 7;              // batch / group
    const int rank = bid >> 3;             // 0..31 within group
    const int lr   = tid >> 3;             // local row 0..31
    const int j    = tid & 7;              // k-slice within row
    const int row  = rank * 32 + lr;

    // W_hh slice (k in [j*128, j*128+128)) — stays register-resident (R4: VGPR=216)
    float4 w4[KV4];
    {
        const float4* whh4 = (const float4*)(W_hh + (size_t)row * RR);
        #pragma unroll
        for (int i = 0; i < KV4; i++) w4[i] = whh4[j * KV4 + i];
    }
    float wfb[12];
    #pragma unroll
    for (int kk = 0; kk < 12; kk++) {
        int k = j * 12 + kk;
        wfb[kk] = (k < FF) ? W_fb[(size_t)row * FF + k]
                           : W_in[(size_t)row * II + (k - FF)];
    }
    const float brow = bias[row];

    __shared__ float hlds[2][1056];      // padded h tile per parity
    __shared__ float ulds[2][8 * 96];    // 8-step u chunks, double buffered

    const float* fbg  = feedback + (size_t)g * TT * FF;
    const float* drg  = driving  + (size_t)g * TT * II;
    float*       outg = out + (size_t)g * TT * RR;

    // u-chunk loader assignment: 192 threads x 1 float4 = 8 steps x 96 floats
    const int  us   = tid / 24;            // step within chunk
    const int  up   = tid % 24;            // float4 within step
    const bool uact = (tid < 192);
    const float* ubase; int ustep, uo;
    if (up < 16) { ubase = fbg; ustep = FF; uo = 4 * up; }
    else         { ubase = drg; ustep = II; uo = 4 * (up - 16); }
    const int uslot = us * 96 + ((up < 16) ? 4 * up : 64 + 4 * (up - 16));

    // stage chunk 0 (steps 0..7)
    if (uact) {
        float4 v = *(const float4*)(ubase + (size_t)us * ustep + uo);
        *(float4*)&ulds[0][uslot] = v;
    }

    float4 hist[8];   // out-row history (valid on lr==rank threads), reg-resident
    __syncthreads();

    for (int t8 = 0; t8 < TT / 8; t8++) {
        #pragma unroll
        for (int s = 0; s < 8; s++) {
            const int t = 8 * t8 + s;
            const int par = t & 1;

            // ---- poll+load h_t: 2 u64 = 4 tagged fp32 (mantissa-LSB tag).
            // No other vmem issued since the last drain -> the tag check's
            // vmcnt(0) waits only on the poll loads themselves.
            const u64* sp = (const u64*)(hbuf + (size_t)par * SLOT_U32 + (size_t)g * RR) + 2 * tid;
            const u64 want = ((u64)((t >> 1) & 1)) * TAGMASK;
            u64 v0 = ld_rlx64(sp), v1 = ld_rlx64(sp + 1);
            while ((v0 & TAGMASK) != want) v0 = ld_rlx64(sp);
            while ((v1 & TAGMASK) != want) v1 = ld_rlx64(sp + 1);
            const float4 f4 = make_float4(
                __uint_as_float((u32)v0), __uint_as_float((u32)(v0 >> 32)),
                __uint_as_float((u32)v1), __uint_as_float((u32)(v1 >> 32)));

            // ---- register history: h_t == out row t-1; slot (t-1)&7 == (s+7)&7
            if (lr == rank) hist[(s + 7) & 7] = f4;

            // ---- stage into padded LDS ----
            *(float4*)&hlds[par][PAD(4 * tid)] = f4;
            __syncthreads();

            // ---- once per chunk: flush 8 buffered out rows (compute phase;
            // store acks drain at the NEXT poll where the spin hides them)
            if (s == 0 && t8 > 0 && lr == rank) {
                #pragma unroll
                for (int r = 0; r < 8; r++)
                    *(float4*)(outg + (size_t)(t - 8 + r) * RR + 4 * tid) = hist[r];
            }

            // ---- once per chunk: issue next u-chunk loads (commit after publish)
            float4 uc;
            const bool udo = (s == 7) && (t8 + 1 < TT / 8) && uact;
            if (udo) uc = *(const float4*)(ubase + (size_t)(8 * (t8 + 1) + us) * ustep + uo);

            // ---- compute (bank-conflict-free j-sliced float4 reads) ----
            float4 acc = make_float4(0.f, 0.f, 0.f, 0.f);
            const float* hb = &hlds[par][j * 132];
            #pragma unroll
            for (int i = 0; i < KV4; i++) {
                float4 hv = *(const float4*)(hb + 4 * i);
                acc.x = fmaf(w4[i].x, hv.x, acc.x);
                acc.y = fmaf(w4[i].y, hv.y, acc.y);
                acc.z = fmaf(w4[i].z, hv.z, acc.z);
                acc.w = fmaf(w4[i].w, hv.w, acc.w);
            }
            {
                const float* uv = &ulds[t8 & 1][s * 96 + j * 12];
                #pragma unroll
                for (int kk = 0; kk < 12; kk++)
                    acc.x = fmaf(wfb[kk], uv[kk], acc.x);
            }

            float ssum = (acc.x + acc.y) + (acc.z + acc.w);
            ssum += __shfl_xor(ssum, 1, 64);
            ssum += __shfl_xor(ssum, 2, 64);
            ssum += __shfl_xor(ssum, 4, 64);

            // ---- publish h_{t+1}: one relaxed tagged u32 ----
            if (j == 0) {
                const float hold = hlds[par][PAD(row)];
                const float hnew = fast_tanh(fmaf(ALPHA, ssum + brow, (1.0f - ALPHA) * hold));
                const u32 bits = (__float_as_uint(hnew) & ~1u) | (u32)(((t + 1) >> 1) & 1);
                st_rlx32(hbuf + (size_t)((t + 1) & 1) * SLOT_U32 + (size_t)g * RR + row, bits);
            }

            // ---- commit u chunk to LDS after publish: the reg-arrival vmcnt
            // drain overlaps the next poll's spin (which waits anyway). The
            // consumers read it after >=1 subsequent __syncthreads.
            if (udo) *(float4*)&ulds[(t8 + 1) & 1][uslot] = uc;
        }
    }

    // ---- tail: poll h_TT (slot 0, tag bit (4096>>1)&1 == 0) -> row 4095,
    // then flush the last 8 rows (4088..4095)
    if (lr == rank) {
        const u64* sp = (const u64*)(hbuf + (size_t)g * RR) + 2 * tid;
        u64 v0 = ld_rlx64(sp), v1 = ld_rlx64(sp + 1);
        while ((v0 & TAGMASK) != 0ull) v0 = ld_rlx64(sp);
        while ((v1 & TAGMASK) != 0ull) v1 = ld_rlx64(sp + 1);
        hist[7] = make_float4(__uint_as_float((u32)v0), __uint_as_float((u32)(v0 >> 32)),
                              __uint_as_float((u32)v1), __uint_as_float((u32)(v1 >> 32)));
        #pragma unroll
        for (int r = 0; r < 8; r++)
            *(float4*)(outg + (size_t)(TT - 8 + r) * RR + 4 * tid) = hist[r];
    }
}

extern "C" void kernel_launch(void* const* d_in, const int* in_sizes, int n_in,
                              void* d_out, int out_size, void* d_ws, size_t ws_size,
                              hipStream_t stream) {
    const float* feedback = (const float*)d_in[0];
    const float* driving  = (const float*)d_in[1];
    const float* W_fb     = (const float*)d_in[2];
    const float* W_in     = (const float*)d_in[3];
    const float* W_hh     = (const float*)d_in[4];
    const float* bias     = (const float*)d_in[5];
    float* out = (float*)d_out;

    u32* hbuf = (u32*)d_ws;
    // 64 KB ws total. Slot 0 = 0x00: tag bit 0 + h = 0.0f == h_0 (readable at
    // t=0). Slot 1 = 0x01 bytes: tag bit 1 != expected 0 at t=1 -> spin until
    // the real h_1 stores land.
    hipMemsetAsync(d_ws, 0x00, SLOT_U32 * sizeof(u32), stream);
    hipMemsetAsync((char*)d_ws + SLOT_U32 * sizeof(u32), 0x01, SLOT_U32 * sizeof(u32), stream);

    void* args[] = { (void*)&feedback, (void*)&driving, (void*)&W_fb, (void*)&W_in,
                     (void*)&W_hh, (void*)&bias, (void*)&out, (void*)&hbuf };
    hipError_t ce = hipLaunchCooperativeKernel((const void*)reservoir_df,
                                               dim3(GROUPS * BPG), dim3(THREADS), args, 0, stream);
    if (ce != hipSuccess) {
        // Safe fallback (R3's silent coop-launch failure): no grid-wide sync is
        // used, only intra-group dataflow; all 256 blocks co-reside regardless.
        hipLaunchKernelGGL(reservoir_df, dim3(GROUPS * BPG), dim3(THREADS), 0, stream,
                           feedback, driving, W_fb, W_in, W_hh, bias, out, hbuf);
    }
}